// Round 7
// baseline (172.990 us; speedup 1.0000x reference)
//
#include <hip/hip_runtime.h>

typedef __bf16 bf16x8 __attribute__((ext_vector_type(8)));
typedef __bf16 bf16x4 __attribute__((ext_vector_type(4)));
typedef float f32x4 __attribute__((ext_vector_type(4)));

__device__ __forceinline__ void async_copy16(const void* g, void* l) {
    __builtin_amdgcn_global_load_lds(
        (const __attribute__((address_space(1))) void*)g,
        (__attribute__((address_space(3))) void*)l, 16, 0, 0);
}

__device__ __forceinline__ int xcd_swz(int bx, int nx) {
    // bijective when nx % 8 == 0 (all our grids)
    return (bx & 7) * (nx >> 3) + (bx >> 3);
}

// ---------------- cvt: x -> bf16, [Wq;Wk] -> bf16, [bq;bk] -> f32 concat ----
__global__ __launch_bounds__(256) void k_cvt(
    const float4* __restrict__ x, const float4* __restrict__ Wq,
    const float4* __restrict__ Wk, const float4* __restrict__ bq,
    const float4* __restrict__ bk,
    bf16x4* __restrict__ xb, bf16x4* __restrict__ Wb,
    float4* __restrict__ biasc) {
    int i = blockIdx.x * 256 + threadIdx.x;
    if (i < 2097152) {
        float4 v = x[i];
        bf16x4 r = {(__bf16)v.x, (__bf16)v.y, (__bf16)v.z, (__bf16)v.w};
        xb[i] = r;
    }
    if (i < 131072) {
        float4 v = (i < 65536) ? Wq[i] : Wk[i - 65536];
        bf16x4 r = {(__bf16)v.x, (__bf16)v.y, (__bf16)v.z, (__bf16)v.w};
        Wb[i] = r;
    }
    if (i < 256) {
        biasc[i] = (i < 128) ? bq[i] : bk[i - 128];
    }
}

// ---------------- fold: xzT[b][d][s] = bf16(x[b][Q(s)][d] / Z_s[s]) --------
// n stored permuted: storage s holds logical n = Q(s) = ((s&3)<<4)|((s>>2)&15)
// within each 64-group. Z is storage-indexed. (unchanged from r5, verified)
__global__ __launch_bounds__(256) void k_fold(
    const __bf16* __restrict__ xb, const float* __restrict__ Z,
    ushort* __restrict__ xzT) {
    __shared__ float tile[64][65];
    __shared__ float zin[64];
    const int b = blockIdx.y;
    const int td = blockIdx.x & 7;
    const int tn = blockIdx.x >> 3;
    const int n0 = tn * 64, d0 = td * 64;
    const int t = threadIdx.x;
    if (t < 64) zin[t] = 1.0f / Z[b * 2048 + n0 + t];
    __syncthreads();
    const int cl = t & 15, c4 = cl * 4, rr = t >> 4;
#pragma unroll
    for (int j = 0; j < 4; ++j) {
        int nr = rr + j * 16;
        bf16x4 v = *(const bf16x4*)&xb[((size_t)b * 2048 + n0 + nr) * 512 + d0 + c4];
        tile[nr][c4 + 0] = (float)v[0];
        tile[nr][c4 + 1] = (float)v[1];
        tile[nr][c4 + 2] = (float)v[2];
        tile[nr][c4 + 3] = (float)v[3];
    }
    __syncthreads();
#pragma unroll
    for (int j2 = 0; j2 < 4; ++j2) {
        int dr = rr + j2 * 16;
        bf16x4 pk;
#pragma unroll
        for (int j = 0; j < 4; ++j)
            pk[j] = (__bf16)(tile[j * 16 + cl][dr] * zin[c4 + j]);
        *(bf16x4*)&xzT[((size_t)b * 512 + d0 + dr) * 2048 + n0 + c4] = pk;
    }
}

// ======== fat bt-GEMM body: 256x128 tile, BK=64, 4 waves, wave 128x64 ======
// C[m,n] = sum_k A[m,k]*B[n,k]. Swizzle involution both sides:
// kbyte ^= ((row&7)<<4). Perm-store P(n)=cl*4+j within 64-groups.
// EPI 0: +bias, bf16 perm-store | EPI 1: exp2(acc*scale2), bf16 perm-store + Z
template <int EPI>
__device__ __forceinline__ void gemm_fat_body(
    const ushort* __restrict__ A, int lda, long sA,
    const ushort* __restrict__ B, int ldb, long sB,
    ushort* __restrict__ C, int ldc, long sC,
    int tiles_n, int K,
    const float* __restrict__ bias, float scale2,
    float* __restrict__ Z, long sZ) {
    __shared__ ushort lA[256 * 64];  // 32 KB
    __shared__ ushort lB[128 * 64];  // 16 KB
    const int b = blockIdx.y;
    A += (size_t)b * sA;
    B += (size_t)b * sB;
    const int bx = xcd_swz(blockIdx.x, gridDim.x);
    const int tm = bx / tiles_n, tn = bx % tiles_n;
    const int t = threadIdx.x;
    const int l = t & 63, w = t >> 6;
    const int wr = w >> 1, wc = w & 1;  // 2 m-halves x 2 n-halves

    f32x4 acc[8][4];
#pragma unroll
    for (int i = 0; i < 8; ++i)
#pragma unroll
        for (int j = 0; j < 4; ++j) acc[i][j] = (f32x4){0.f, 0.f, 0.f, 0.f};

    const int soff = t * 16;
    const int skb = soff & 127;

    for (int k0 = 0; k0 < K; k0 += 64) {
#pragma unroll
        for (int p = 0; p < 8; ++p) {  // A: 256 rows
            int off = p * 4096 + soff;
            int row = off >> 7;
            int kswz = skb ^ ((row & 7) << 4);
            async_copy16(A + (size_t)(tm * 256 + row) * lda + k0 + (kswz >> 1),
                         (char*)lA + off);
        }
#pragma unroll
        for (int p = 0; p < 4; ++p) {  // B: 128 rows
            int off = p * 4096 + soff;
            int row = off >> 7;
            int kswz = skb ^ ((row & 7) << 4);
            async_copy16(B + (size_t)(tn * 128 + row) * ldb + k0 + (kswz >> 1),
                         (char*)lB + off);
        }
        __syncthreads();
#pragma unroll
        for (int ks = 0; ks < 2; ++ks) {
            bf16x8 af[8], bfr[4];
#pragma unroll
            for (int i = 0; i < 8; ++i) {
                int row = wr * 128 + i * 16 + (l & 15);
                int colb = (ks * 64 + (l >> 4) * 16) ^ ((row & 7) << 4);
                af[i] = *(const bf16x8*)((const char*)lA + row * 128 + colb);
            }
#pragma unroll
            for (int j = 0; j < 4; ++j) {
                int row = wc * 64 + j * 16 + (l & 15);
                int colb = (ks * 64 + (l >> 4) * 16) ^ ((row & 7) << 4);
                bfr[j] = *(const bf16x8*)((const char*)lB + row * 128 + colb);
            }
#pragma unroll
            for (int i = 0; i < 8; ++i)
#pragma unroll
                for (int j = 0; j < 4; ++j)
                    acc[i][j] = __builtin_amdgcn_mfma_f32_16x16x32_bf16(
                        af[i], bfr[j], acc[i][j], 0, 0, 0);
        }
        __syncthreads();
    }

    const int mb = tm * 256 + wr * 128;
    const int nb = tn * 128 + wc * 64;
    const int cl = l & 15;
    ushort* Cp = C + (size_t)b * sC;

    if (EPI == 0) {
#pragma unroll
        for (int i = 0; i < 8; ++i)
#pragma unroll
            for (int q = 0; q < 4; ++q) {
                int row = mb + i * 16 + (l >> 4) * 4 + q;
                bf16x4 pk;
#pragma unroll
                for (int j = 0; j < 4; ++j)
                    pk[j] = (__bf16)(acc[i][j][q] + bias[nb + j * 16 + cl]);
                *(bf16x4*)&Cp[(size_t)row * ldc + nb + cl * 4] = pk;
            }
    } else {
        float colsum[4] = {0.f, 0.f, 0.f, 0.f};
#pragma unroll
        for (int i = 0; i < 8; ++i)
#pragma unroll
            for (int q = 0; q < 4; ++q) {
                int row = mb + i * 16 + (l >> 4) * 4 + q;
                bf16x4 pk;
#pragma unroll
                for (int j = 0; j < 4; ++j) {
                    float e = __builtin_amdgcn_exp2f(acc[i][j][q] * scale2);
                    colsum[j] += e;
                    pk[j] = (__bf16)e;
                }
                *(bf16x4*)&Cp[(size_t)row * ldc + nb + cl * 4] = pk;
            }
#pragma unroll
        for (int j = 0; j < 4; ++j) {
            float s = colsum[j];
            s += __shfl_xor(s, 16);
            s += __shfl_xor(s, 32);
            if (l < 16) atomicAdd(&Z[b * sZ + nb + l * 4 + j], s);
        }
    }
}

__global__ __launch_bounds__(256) void k_proj(
    const ushort* __restrict__ A, const ushort* __restrict__ B,
    ushort* __restrict__ C, const float* __restrict__ bias) {
    gemm_fat_body<0>(A, 512, 0L, B, 512, 0L, C, 1024, 0L,
                     8, 512, bias, 0.f, nullptr, 0L);
}

__global__ __launch_bounds__(256) void k_escore(
    const ushort* __restrict__ A, const ushort* __restrict__ B,
    ushort* __restrict__ C, float* __restrict__ Z) {
    // scale2 = (1/sqrt(512)) * log2(e)
    gemm_fat_body<1>(A, 1024, 2048L * 1024, B, 1024, 2048L * 1024,
                     C, 2048, 2048L * 2048, 16, 512,
                     nullptr, 0.063758716f, Z, 2048L);
}

// ======== classic 128x128 bt-GEMM (r1-proven) for the output GEMM ==========
__global__ __launch_bounds__(256) void k_out(
    const ushort* __restrict__ A, const ushort* __restrict__ B,
    float* __restrict__ C) {
    __shared__ ushort lA[128 * 64];  // 16 KB
    __shared__ ushort lB[128 * 64];  // 16 KB
    const int lda = 2048, ldb = 2048, ldc = 512, tiles_n = 4, K = 2048;
    const int b = blockIdx.y;
    A += (size_t)b * 2048L * 2048;
    B += (size_t)b * 512L * 2048;
    const int bx = xcd_swz(blockIdx.x, gridDim.x);
    const int tm = bx / tiles_n, tn = bx % tiles_n;
    const int t = threadIdx.x;
    const int l = t & 63, w = t >> 6;
    const int wr = w >> 1, wc = w & 1;

    f32x4 acc[4][4];
#pragma unroll
    for (int i = 0; i < 4; ++i)
#pragma unroll
        for (int j = 0; j < 4; ++j) acc[i][j] = (f32x4){0.f, 0.f, 0.f, 0.f};

    for (int k0 = 0; k0 < K; k0 += 64) {
#pragma unroll
        for (int p = 0; p < 4; ++p) {
            int off = p * 4096 + t * 16;
            int row = off >> 7;
            int kb = off & 127;
            int kswz = kb ^ ((row & 7) << 4);
            async_copy16(A + (size_t)(tm * 128 + row) * lda + k0 + (kswz >> 1),
                         (char*)lA + off);
            async_copy16(B + (size_t)(tn * 128 + row) * ldb + k0 + (kswz >> 1),
                         (char*)lB + off);
        }
        __syncthreads();
#pragma unroll
        for (int ks = 0; ks < 2; ++ks) {
            bf16x8 af[4], bfr[4];
#pragma unroll
            for (int i = 0; i < 4; ++i) {
                int row = wr * 64 + i * 16 + (l & 15);
                int colb = (ks * 64 + (l >> 4) * 16) ^ ((row & 7) << 4);
                af[i] = *(const bf16x8*)((const char*)lA + row * 128 + colb);
            }
#pragma unroll
            for (int j = 0; j < 4; ++j) {
                int row = wc * 64 + j * 16 + (l & 15);
                int colb = (ks * 64 + (l >> 4) * 16) ^ ((row & 7) << 4);
                bfr[j] = *(const bf16x8*)((const char*)lB + row * 128 + colb);
            }
#pragma unroll
            for (int i = 0; i < 4; ++i)
#pragma unroll
                for (int j = 0; j < 4; ++j)
                    acc[i][j] = __builtin_amdgcn_mfma_f32_16x16x32_bf16(
                        af[i], bfr[j], acc[i][j], 0, 0, 0);
        }
        __syncthreads();
    }

    const int mb = tm * 128 + wr * 64;
    const int nb = tn * 128 + wc * 64;
    float* Cp = C + (size_t)b * 2048L * 512;
#pragma unroll
    for (int i = 0; i < 4; ++i)
#pragma unroll
        for (int j = 0; j < 4; ++j)
#pragma unroll
            for (int q = 0; q < 4; ++q) {
                int row = mb + i * 16 + (l >> 4) * 4 + q;
                int col = nb + j * 16 + (l & 15);
                Cp[(size_t)row * ldc + col] = acc[i][j][q];
            }
}

extern "C" void kernel_launch(void* const* d_in, const int* in_sizes, int n_in,
                              void* d_out, int out_size, void* d_ws, size_t ws_size,
                              hipStream_t stream) {
    const float* x  = (const float*)d_in[0];
    const float* Wq = (const float*)d_in[1];
    const float* bq = (const float*)d_in[2];
    const float* Wk = (const float*)d_in[3];
    const float* bk = (const float*)d_in[4];

    char* ws = (char*)d_ws;
    ushort* xb    = (ushort*)(ws);                 // 16 MB
    ushort* Wb    = (ushort*)(ws + 16777216);      //  1 MB
    float*  biasc = (float*) (ws + 17825792);      //  4 KB
    float*  Z     = (float*) (ws + 17829888);      // 64 KB (storage-indexed)
    ushort* qkb   = (ushort*)(ws + 17895424);      // 32 MB (reused as xzT)
    ushort* E     = (ushort*)(ws + 51449856);      // 64 MB
    ushort* xzT   = qkb;   // qkb dead after E-pass

    (void)hipMemsetAsync(Z, 0, 16384 * 4, stream);

    k_cvt<<<8192, 256, 0, stream>>>(
        (const float4*)x, (const float4*)Wq, (const float4*)Wk,
        (const float4*)bq, (const float4*)bk,
        (bf16x4*)xb, (bf16x4*)Wb, (float4*)biasc);

    // proj: qk[m, P(h)] = x[m,:] . W[h,:] + bias[h]  (M=16384, N=1024, K=512)
    k_proj<<<dim3(512, 1), 256, 0, stream>>>(xb, Wb, qkb, biasc);

    // E-pass: E[b][m][P(n)] = exp(scale * k[m].q[n]); Z_s += col sums
    k_escore<<<dim3(128, 8), 256, 0, stream>>>(qkb + 512, qkb, E, Z);

    // fold: xzT[b][d][s] = bf16(x[b][Q(s)][d] / Z_s[s])
    k_fold<<<dim3(256, 8), 256, 0, stream>>>((const __bf16*)xb, Z, xzT);

    // out: out[b][m][d] = sum_s E[b][m][s] * xzT[b][d][s]   (fp32 store)
    k_out<<<dim3(64, 8), 256, 0, stream>>>(E, xzT, (float*)d_out);
}

// Round 8
// 132.566 us; speedup vs baseline: 1.3049x; 1.3049x over previous
//
#include <hip/hip_runtime.h>

typedef __bf16 bf16x8 __attribute__((ext_vector_type(8)));
typedef __bf16 bf16x4 __attribute__((ext_vector_type(4)));
typedef float f32x4 __attribute__((ext_vector_type(4)));

__device__ __forceinline__ void async_copy16(const void* g, void* l) {
    __builtin_amdgcn_global_load_lds(
        (const __attribute__((address_space(1))) void*)g,
        (__attribute__((address_space(3))) void*)l, 16, 0, 0);
}

__device__ __forceinline__ int xcd_swz(int bx, int nx) {
    // bijective when nx % 8 == 0 (all our grids)
    return (bx & 7) * (nx >> 3) + (bx >> 3);
}

// ---------------- cvt: x -> bf16, [Wq;Wk] -> bf16, [bq;bk] -> f32 concat ----
__global__ __launch_bounds__(256) void k_cvt(
    const float4* __restrict__ x, const float4* __restrict__ Wq,
    const float4* __restrict__ Wk, const float4* __restrict__ bq,
    const float4* __restrict__ bk,
    bf16x4* __restrict__ xb, bf16x4* __restrict__ Wb,
    float4* __restrict__ biasc) {
    int i = blockIdx.x * 256 + threadIdx.x;
    if (i < 2097152) {
        float4 v = x[i];
        bf16x4 r = {(__bf16)v.x, (__bf16)v.y, (__bf16)v.z, (__bf16)v.w};
        xb[i] = r;
    }
    if (i < 131072) {
        float4 v = (i < 65536) ? Wq[i] : Wk[i - 65536];
        bf16x4 r = {(__bf16)v.x, (__bf16)v.y, (__bf16)v.z, (__bf16)v.w};
        Wb[i] = r;
    }
    if (i < 256) {
        biasc[i] = (i < 128) ? bq[i] : bk[i - 128];
    }
}

// ---------------- fold: xzT[b][d][s] = bf16(x[b][Q(s)][d] / Z_s[s]) --------
// n stored permuted: storage s holds logical n = Q(s) = ((s&3)<<4)|((s>>2)&15)
// within each 64-group. Z is storage-indexed. (r5-verified)
__global__ __launch_bounds__(256) void k_fold(
    const __bf16* __restrict__ xb, const float* __restrict__ Z,
    ushort* __restrict__ xzT) {
    __shared__ float tile[64][65];
    __shared__ float zin[64];
    const int b = blockIdx.y;
    const int td = blockIdx.x & 7;
    const int tn = blockIdx.x >> 3;
    const int n0 = tn * 64, d0 = td * 64;
    const int t = threadIdx.x;
    if (t < 64) zin[t] = 1.0f / Z[b * 2048 + n0 + t];
    __syncthreads();
    const int cl = t & 15, c4 = cl * 4, rr = t >> 4;
#pragma unroll
    for (int j = 0; j < 4; ++j) {
        int nr = rr + j * 16;
        bf16x4 v = *(const bf16x4*)&xb[((size_t)b * 2048 + n0 + nr) * 512 + d0 + c4];
        tile[nr][c4 + 0] = (float)v[0];
        tile[nr][c4 + 1] = (float)v[1];
        tile[nr][c4 + 2] = (float)v[2];
        tile[nr][c4 + 3] = (float)v[3];
    }
    __syncthreads();
#pragma unroll
    for (int j2 = 0; j2 < 4; ++j2) {
        int dr = rr + j2 * 16;
        bf16x4 pk;
#pragma unroll
        for (int j = 0; j < 4; ++j)
            pk[j] = (__bf16)(tile[j * 16 + cl][dr] * zin[c4 + j]);
        *(bf16x4*)&xzT[((size_t)b * 512 + d0 + dr) * 2048 + n0 + c4] = pk;
    }
}

// ===== 2-deep counted-vmcnt bt-GEMM: C[m,n] = sum_k A[m,k]*B[n,k] ==========
// 128x128 tile, BK=64, 4 waves (2x2), 16x16x32 MFMA, r1-proven fragment
// geometry + involution swizzle (kbyte ^= (row&7)<<4, both sides).
// Pipeline: 2 LDS buffers, 2 K-tiles in flight. Per K-tile:
//   bulk ds_read (16 x b128) -> lgkmcnt(0) -> barrier       [WAR join]
//   stage(kt+2) into the buffer just read (8 loads stay in flight ~2 K-tiles)
//   32 MFMA (setprio-wrapped)
//   vmcnt(8) counted (vmcnt(0) only at tail) -> barrier      [RAW join]
// EPI 0: +bias, bf16 perm-store | EPI 1: exp2, bf16 perm-store + Z | EPI 2: f32
template <int EPI>
__device__ __forceinline__ void gemm_core(
    const ushort* __restrict__ A, int lda, long sA,
    const ushort* __restrict__ B, int ldb, long sB,
    void* __restrict__ C, int ldc, long sC,
    int tiles_n, int K,
    const float* __restrict__ bias, float scale2,
    float* __restrict__ Z, long sZ) {
    __shared__ ushort lA[2][8192];  // 2 x 16 KB
    __shared__ ushort lB[2][8192];  // 2 x 16 KB
    const int b = blockIdx.y;
    A += (size_t)b * sA;
    B += (size_t)b * sB;
    const int bx = xcd_swz(blockIdx.x, gridDim.x);
    const int tm = bx / tiles_n, tn = bx % tiles_n;
    const int t = threadIdx.x;
    const int l = t & 63, w = t >> 6;
    const int wr = w >> 1, wc = w & 1;

    size_t gA[4], gB[4];
    int dOf[4];
#pragma unroll
    for (int p = 0; p < 4; ++p) {
        int off = p * 4096 + t * 16;
        int row = off >> 7, kb = off & 127;
        int kswz = kb ^ ((row & 7) << 4);
        gA[p] = (size_t)(tm * 128 + row) * lda + (kswz >> 1);
        gB[p] = (size_t)(tn * 128 + row) * ldb + (kswz >> 1);
        dOf[p] = off;
    }
    auto stage = [&](int buf, int k0) {
#pragma unroll
        for (int p = 0; p < 4; ++p) {
            async_copy16(A + gA[p] + k0, (char*)lA[buf] + dOf[p]);
            async_copy16(B + gB[p] + k0, (char*)lB[buf] + dOf[p]);
        }
    };

    f32x4 acc[4][4];
#pragma unroll
    for (int i = 0; i < 4; ++i)
#pragma unroll
        for (int j = 0; j < 4; ++j) acc[i][j] = (f32x4){0.f, 0.f, 0.f, 0.f};

    const int nk = K >> 6;
    // prologue: 2 K-tiles issued; wait only for the first (8 newest in flight)
    stage(0, 0);
    stage(1, 64);
    asm volatile("s_waitcnt vmcnt(8)" ::: "memory");
    __builtin_amdgcn_s_barrier();
    asm volatile("" ::: "memory");

    for (int kt = 0; kt < nk; ++kt) {
        const int cur = kt & 1;
        // bulk fragment reads for the whole K-tile (both k-halves)
        bf16x8 af[4][2], bg[4][2];
#pragma unroll
        for (int ks = 0; ks < 2; ++ks)
#pragma unroll
            for (int i = 0; i < 4; ++i) {
                int rowA = wr * 64 + i * 16 + (l & 15);
                int colA = (ks * 64 + (l >> 4) * 16) ^ ((rowA & 7) << 4);
                af[i][ks] = *(const bf16x8*)((const char*)lA[cur] + rowA * 128 + colA);
                int rowB = wc * 64 + i * 16 + (l & 15);
                int colB = (ks * 64 + (l >> 4) * 16) ^ ((rowB & 7) << 4);
                bg[i][ks] = *(const bf16x8*)((const char*)lB[cur] + rowB * 128 + colB);
            }
        asm volatile("s_waitcnt lgkmcnt(0)" ::: "memory");
        __builtin_amdgcn_sched_barrier(0);
        __builtin_amdgcn_s_barrier();       // all waves done reading buf[cur]
        asm volatile("" ::: "memory");
        if (kt + 2 < nk) stage(cur, (kt + 2) << 6);  // refill just-read buffer
        __builtin_amdgcn_sched_barrier(0);
        __builtin_amdgcn_s_setprio(1);
#pragma unroll
        for (int ks = 0; ks < 2; ++ks)
#pragma unroll
            for (int i = 0; i < 4; ++i)
#pragma unroll
                for (int j = 0; j < 4; ++j)
                    acc[i][j] = __builtin_amdgcn_mfma_f32_16x16x32_bf16(
                        af[i][ks], bg[j][ks], acc[i][j], 0, 0, 0);
        __builtin_amdgcn_s_setprio(0);
        // counted wait: oldest 8 (next K-tile's loads) landed; kt+2's stay in flight
        if (kt + 2 < nk) {
            asm volatile("s_waitcnt vmcnt(8)" ::: "memory");
        } else {
            asm volatile("s_waitcnt vmcnt(0)" ::: "memory");
        }
        __builtin_amdgcn_s_barrier();
        asm volatile("" ::: "memory");
    }

    const int mb = tm * 128 + wr * 64;
    const int nb = tn * 128 + wc * 64;
    const int cl = l & 15;

    if (EPI == 0) {
        ushort* Cp = (ushort*)C + (size_t)b * sC;
#pragma unroll
        for (int i = 0; i < 4; ++i)
#pragma unroll
            for (int q = 0; q < 4; ++q) {
                int row = mb + i * 16 + (l >> 4) * 4 + q;
                bf16x4 pk;
#pragma unroll
                for (int j = 0; j < 4; ++j)
                    pk[j] = (__bf16)(acc[i][j][q] + bias[nb + j * 16 + cl]);
                *(bf16x4*)&Cp[(size_t)row * ldc + nb + cl * 4] = pk;
            }
    } else if (EPI == 1) {
        ushort* Cp = (ushort*)C + (size_t)b * sC;
        float colsum[4] = {0.f, 0.f, 0.f, 0.f};
#pragma unroll
        for (int i = 0; i < 4; ++i)
#pragma unroll
            for (int q = 0; q < 4; ++q) {
                int row = mb + i * 16 + (l >> 4) * 4 + q;
                bf16x4 pk;
#pragma unroll
                for (int j = 0; j < 4; ++j) {
                    float e = __builtin_amdgcn_exp2f(acc[i][j][q] * scale2);
                    colsum[j] += e;
                    pk[j] = (__bf16)e;
                }
                *(bf16x4*)&Cp[(size_t)row * ldc + nb + cl * 4] = pk;
            }
#pragma unroll
        for (int j = 0; j < 4; ++j) {
            float s = colsum[j];
            s += __shfl_xor(s, 16);
            s += __shfl_xor(s, 32);
            if (l < 16) atomicAdd(&Z[b * sZ + nb + l * 4 + j], s);
        }
    } else {
        float* Cp = (float*)C + (size_t)b * sC;
#pragma unroll
        for (int i = 0; i < 4; ++i)
#pragma unroll
            for (int j = 0; j < 4; ++j)
#pragma unroll
                for (int q = 0; q < 4; ++q) {
                    int row = mb + i * 16 + (l >> 4) * 4 + q;
                    int col = nb + j * 16 + cl;
                    Cp[(size_t)row * ldc + col] = acc[i][j][q];
                }
    }
}

__global__ __launch_bounds__(256) void k_proj(
    const ushort* __restrict__ A, const ushort* __restrict__ B,
    ushort* __restrict__ C, const float* __restrict__ bias) {
    gemm_core<0>(A, 512, 0L, B, 512, 0L, C, 1024, 0L,
                 8, 512, bias, 0.f, nullptr, 0L);
}

__global__ __launch_bounds__(256) void k_escore(
    const ushort* __restrict__ A, const ushort* __restrict__ B,
    ushort* __restrict__ C, float* __restrict__ Z) {
    // scale2 = (1/sqrt(512)) * log2(e)
    gemm_core<1>(A, 1024, 2048L * 1024, B, 1024, 2048L * 1024,
                 C, 2048, 2048L * 2048, 16, 512,
                 nullptr, 0.063758716f, Z, 2048L);
}

__global__ __launch_bounds__(256) void k_out(
    const ushort* __restrict__ A, const ushort* __restrict__ B,
    float* __restrict__ C) {
    gemm_core<2>(A, 2048, 2048L * 2048, B, 2048, 512L * 2048,
                 C, 512, 2048L * 512, 4, 2048,
                 nullptr, 0.f, nullptr, 0L);
}

extern "C" void kernel_launch(void* const* d_in, const int* in_sizes, int n_in,
                              void* d_out, int out_size, void* d_ws, size_t ws_size,
                              hipStream_t stream) {
    const float* x  = (const float*)d_in[0];
    const float* Wq = (const float*)d_in[1];
    const float* bq = (const float*)d_in[2];
    const float* Wk = (const float*)d_in[3];
    const float* bk = (const float*)d_in[4];

    char* ws = (char*)d_ws;
    ushort* xb    = (ushort*)(ws);                 // 16 MB
    ushort* Wb    = (ushort*)(ws + 16777216);      //  1 MB
    float*  biasc = (float*) (ws + 17825792);      //  4 KB
    float*  Z     = (float*) (ws + 17829888);      // 64 KB (storage-indexed)
    ushort* qkb   = (ushort*)(ws + 17895424);      // 32 MB (reused as xzT)
    ushort* E     = (ushort*)(ws + 51449856);      // 64 MB
    ushort* xzT   = qkb;   // qkb dead after E-pass

    (void)hipMemsetAsync(Z, 0, 16384 * 4, stream);

    k_cvt<<<8192, 256, 0, stream>>>(
        (const float4*)x, (const float4*)Wq, (const float4*)Wk,
        (const float4*)bq, (const float4*)bk,
        (bf16x4*)xb, (bf16x4*)Wb, (float4*)biasc);

    // proj: qk[m, P(h)] = x[m,:] . W[h,:] + bias[h]  (M=16384, N=1024, K=512)
    k_proj<<<dim3(1024, 1), 256, 0, stream>>>(xb, Wb, qkb, biasc);

    // E-pass: E[b][m][P(n)] = exp(scale * k[m].q[n]); Z_s += col sums
    k_escore<<<dim3(256, 8), 256, 0, stream>>>(qkb + 512, qkb, E, Z);

    // fold: xzT[b][d][s] = bf16(x[b][Q(s)][d] / Z_s[s])
    k_fold<<<dim3(256, 8), 256, 0, stream>>>((const __bf16*)xb, Z, xzT);

    // out: out[b][m][d] = sum_s E[b][m][s] * xzT[b][d][s]   (fp32 store)
    k_out<<<dim3(64, 8), 256, 0, stream>>>(E, xzT, (float*)d_out);
}

// Round 9
// 127.453 us; speedup vs baseline: 1.3573x; 1.0401x over previous
//
#include <hip/hip_runtime.h>

typedef __bf16 bf16x8 __attribute__((ext_vector_type(8)));
typedef __bf16 bf16x4 __attribute__((ext_vector_type(4)));
typedef float f32x4 __attribute__((ext_vector_type(4)));

__device__ __forceinline__ void async_copy16(const void* g, void* l) {
    __builtin_amdgcn_global_load_lds(
        (const __attribute__((address_space(1))) void*)g,
        (__attribute__((address_space(3))) void*)l, 16, 0, 0);
}

__device__ __forceinline__ int xcd_swz(int bx, int nx) {
    return (bx & 7) * (nx >> 3) + (bx >> 3);  // bijective, nx % 8 == 0
}

// ---------------- cvt ------------------------------------------------------
__global__ __launch_bounds__(256) void k_cvt(
    const float4* __restrict__ x, const float4* __restrict__ Wq,
    const float4* __restrict__ Wk, const float4* __restrict__ bq,
    const float4* __restrict__ bk,
    bf16x4* __restrict__ xb, bf16x4* __restrict__ Wb,
    float4* __restrict__ biasc) {
    int i = blockIdx.x * 256 + threadIdx.x;
    if (i < 2097152) {
        float4 v = x[i];
        bf16x4 r = {(__bf16)v.x, (__bf16)v.y, (__bf16)v.z, (__bf16)v.w};
        xb[i] = r;
    }
    if (i < 131072) {
        float4 v = (i < 65536) ? Wq[i] : Wk[i - 65536];
        bf16x4 r = {(__bf16)v.x, (__bf16)v.y, (__bf16)v.z, (__bf16)v.w};
        Wb[i] = r;
    }
    if (i < 256) biasc[i] = (i < 128) ? bq[i] : bk[i - 128];
}

// ---------------- fold (r5-verified) ---------------------------------------
__global__ __launch_bounds__(256) void k_fold(
    const __bf16* __restrict__ xb, const float* __restrict__ Z,
    ushort* __restrict__ xzT) {
    __shared__ float tile[64][65];
    __shared__ float zin[64];
    const int b = blockIdx.y;
    const int td = blockIdx.x & 7;
    const int tn = blockIdx.x >> 3;
    const int n0 = tn * 64, d0 = td * 64;
    const int t = threadIdx.x;
    if (t < 64) zin[t] = 1.0f / Z[b * 2048 + n0 + t];
    __syncthreads();
    const int cl = t & 15, c4 = cl * 4, rr = t >> 4;
#pragma unroll
    for (int j = 0; j < 4; ++j) {
        int nr = rr + j * 16;
        bf16x4 v = *(const bf16x4*)&xb[((size_t)b * 2048 + n0 + nr) * 512 + d0 + c4];
        tile[nr][c4 + 0] = (float)v[0];
        tile[nr][c4 + 1] = (float)v[1];
        tile[nr][c4 + 2] = (float)v[2];
        tile[nr][c4 + 3] = (float)v[3];
    }
    __syncthreads();
#pragma unroll
    for (int j2 = 0; j2 < 4; ++j2) {
        int dr = rr + j2 * 16;
        bf16x4 pk;
#pragma unroll
        for (int j = 0; j < 4; ++j)
            pk[j] = (__bf16)(tile[j * 16 + cl][dr] * zin[c4 + j]);
        *(bf16x4*)&xzT[((size_t)b * 512 + d0 + dr) * 2048 + n0 + c4] = pk;
    }
}

// ===== 8-phase 256x256 bt-GEMM, BK=128/iter (2 K-steps), 512 thr, 8 waves ==
// Regions (16KB each): A/B x dbuf(2) x khalf(2). Region = 256 rows x 32 k,
// stored as 128 phys rows x 128B (row pair), slot swizzle:
//   byte = P*128 + ((((r&1)<<2)|g) ^ (P&7))*16,  r=row, P=r>>1, g=16B-col.
// Stage: linear LDS dest (global_load_lds), inverse-swizzled global source.
// Schedule per iter (verified ring): phases consume (d,ks,isub) =
//  (0,0,0)(0,0,1)(0,1,0)(0,1,1)(1,0,0)(1,0,1)(1,1,0)(1,1,1);
// stage slots: ph1 B-d1k1@kb+96, ph2 A-d1k1@kb+96, ph3 B-d0k0@kn,
//  ph4 A-d0k0@kn +vmcnt(4), ph5 B-d0k1@kn+32, ph6 A-d0k1@kn+32,
//  ph7 B-d1k0@kn+64, ph8 A-d1k0@kn+64 +vmcnt(4). One barrier/phase.
// Prologue: stage Bd0k0,Ad0k0@0, Bd0k1,Ad0k1@32, Bd1k0,Ad1k0@64; vmcnt(4).
template <int EPI>
__device__ __forceinline__ void gemm8p(
    const ushort* __restrict__ A, int lda, long sA,
    const ushort* __restrict__ B, int ldb, long sB,
    ushort* __restrict__ C, int ldc, long sC,
    int tiles_n, int K,
    const float* __restrict__ bias, float scale2,
    float* __restrict__ Z, long sZ) {
    extern __shared__ char lds[];  // 128 KB: A regions @0, B regions @65536
    const int b = blockIdx.y;
    A += (size_t)b * sA;
    B += (size_t)b * sB;
    const int bx = xcd_swz(blockIdx.x, gridDim.x);
    const int tm = bx / tiles_n, tn = bx % tiles_n;
    const int t = threadIdx.x;
    const int l = t & 63, w = t >> 6;
    const int wr = w >> 2, wc = w & 3;   // 2 x 4 waves, wave tile 128 x 64
    const int l15 = l & 15, g16 = l >> 4;

    // stage constants: p in {0,1}, off = p*8192 + t*16
    size_t gAo[2], gBo[2];
    int dst[2];
#pragma unroll
    for (int p = 0; p < 2; ++p) {
        int off = p * 8192 + t * 16;
        int P = off >> 7, sl = (off >> 4) & 7;
        int u = sl ^ (P & 7);
        int rg = 2 * P + (u >> 2);        // logical row 0..255
        int kb8 = (u & 3) * 8;            // k-elem offset within 32
        gAo[p] = (size_t)(tm * 256 + rg) * lda + kb8;
        gBo[p] = (size_t)(tn * 256 + rg) * ldb + kb8;
        dst[p] = off;
    }

#define REG_A(d, ks) (((d) * 2 + (ks)) * 16384)
#define REG_B(d, ks) (65536 + ((d) * 2 + (ks)) * 16384)
#define STG_A(d, ks, kk)                                              \
    { int ro = REG_A(d, ks);                                          \
      async_copy16(A + gAo[0] + (kk), lds + ro + dst[0]);             \
      async_copy16(A + gAo[1] + (kk), lds + ro + dst[1]); }
#define STG_B(d, ks, kk)                                              \
    { int ro = REG_B(d, ks);                                          \
      async_copy16(B + gBo[0] + (kk), lds + ro + dst[0]);             \
      async_copy16(B + gBo[1] + (kk), lds + ro + dst[1]); }

    auto rdoff = [&](int row) {
        int P = row >> 1;
        int slot = (((row & 1) << 2) | g16) ^ (P & 7);
        return P * 128 + slot * 16;
    };

    f32x4 acc[8][4];
#pragma unroll
    for (int i = 0; i < 8; ++i)
#pragma unroll
        for (int j = 0; j < 4; ++j) acc[i][j] = (f32x4){0.f, 0.f, 0.f, 0.f};

    bf16x8 af[4], bg[4];

#define RD_B(d, ks)                                                   \
    _Pragma("unroll") for (int j = 0; j < 4; ++j)                     \
        bg[j] = *(const bf16x8*)(lds + REG_B(d, ks) +                 \
                                 rdoff(wc * 64 + j * 16 + l15));
#define RD_A(d, ks, isub)                                             \
    _Pragma("unroll") for (int i = 0; i < 4; ++i)                     \
        af[i] = *(const bf16x8*)(lds + REG_A(d, ks) +                 \
                                 rdoff(wr * 128 + (isub) * 64 + i * 16 + l15));
#define DO_MFMA(isub)                                                 \
    __builtin_amdgcn_s_setprio(1);                                    \
    _Pragma("unroll") for (int i = 0; i < 4; ++i)                     \
        _Pragma("unroll") for (int j = 0; j < 4; ++j)                 \
            acc[(isub) * 4 + i][j] = __builtin_amdgcn_mfma_f32_16x16x32_bf16( \
                af[i], bg[j], acc[(isub) * 4 + i][j], 0, 0, 0);       \
    __builtin_amdgcn_s_setprio(0);
#define SYNC_LGKM                                                     \
    asm volatile("s_waitcnt lgkmcnt(0)" ::: "memory");                \
    __builtin_amdgcn_sched_barrier(0);
#define ENDPH(vm)                                                     \
    if (vm) asm volatile("s_waitcnt vmcnt(4)" ::: "memory");          \
    __builtin_amdgcn_s_barrier();                                     \
    asm volatile("" ::: "memory");                                    \
    __builtin_amdgcn_sched_barrier(0);

    // prologue
    STG_B(0, 0, 0); STG_A(0, 0, 0);
    STG_B(0, 1, 32); STG_A(0, 1, 32);
    STG_B(1, 0, 64); STG_A(1, 0, 64);
    asm volatile("s_waitcnt vmcnt(4)" ::: "memory");
    __builtin_amdgcn_s_barrier();
    asm volatile("" ::: "memory");

    const int NI = K >> 7;
    for (int it = 0; it < NI; ++it) {
        const int kb = it << 7;
        const int kn = (it + 1 < NI) ? (kb + 128) : kb;
        // PH1
        RD_B(0, 0); RD_A(0, 0, 0); STG_B(1, 1, kb + 96);
        SYNC_LGKM; DO_MFMA(0); ENDPH(false);
        // PH2
        RD_A(0, 0, 1); STG_A(1, 1, kb + 96);
        SYNC_LGKM; DO_MFMA(1); ENDPH(false);
        // PH3
        RD_B(0, 1); RD_A(0, 1, 0); STG_B(0, 0, kn);
        SYNC_LGKM; DO_MFMA(0); ENDPH(false);
        // PH4
        RD_A(0, 1, 1); STG_A(0, 0, kn);
        SYNC_LGKM; DO_MFMA(1); ENDPH(true);
        // PH5
        RD_B(1, 0); RD_A(1, 0, 0); STG_B(0, 1, kn + 32);
        SYNC_LGKM; DO_MFMA(0); ENDPH(false);
        // PH6
        RD_A(1, 0, 1); STG_A(0, 1, kn + 32);
        SYNC_LGKM; DO_MFMA(1); ENDPH(false);
        // PH7
        RD_B(1, 1); RD_A(1, 1, 0); STG_B(1, 0, kn + 64);
        SYNC_LGKM; DO_MFMA(0); ENDPH(false);
        // PH8
        RD_A(1, 1, 1); STG_A(1, 0, kn + 64);
        SYNC_LGKM; DO_MFMA(1); ENDPH(true);
    }
    asm volatile("s_waitcnt vmcnt(0)" ::: "memory");  // drain tail stages

    const int mb = tm * 256 + wr * 128;
    const int nb = tn * 256 + wc * 64;
    const int cl = l15;
    ushort* Cp = C + (size_t)b * sC;

    if (EPI == 0) {
#pragma unroll
        for (int i = 0; i < 8; ++i)
#pragma unroll
            for (int q = 0; q < 4; ++q) {
                int row = mb + i * 16 + (l >> 4) * 4 + q;
                bf16x4 pk;
#pragma unroll
                for (int j = 0; j < 4; ++j)
                    pk[j] = (__bf16)(acc[i][j][q] + bias[nb + j * 16 + cl]);
                *(bf16x4*)&Cp[(size_t)row * ldc + nb + cl * 4] = pk;
            }
    } else {
        float colsum[4] = {0.f, 0.f, 0.f, 0.f};
#pragma unroll
        for (int i = 0; i < 8; ++i)
#pragma unroll
            for (int q = 0; q < 4; ++q) {
                int row = mb + i * 16 + (l >> 4) * 4 + q;
                bf16x4 pk;
#pragma unroll
                for (int j = 0; j < 4; ++j) {
                    float e = __builtin_amdgcn_exp2f(acc[i][j][q] * scale2);
                    colsum[j] += e;
                    pk[j] = (__bf16)e;
                }
                *(bf16x4*)&Cp[(size_t)row * ldc + nb + cl * 4] = pk;
            }
#pragma unroll
        for (int j = 0; j < 4; ++j) {
            float s = colsum[j];
            s += __shfl_xor(s, 16);
            s += __shfl_xor(s, 32);
            if (l < 16) atomicAdd(&Z[b * sZ + nb + l * 4 + j], s);
        }
    }
#undef REG_A
#undef REG_B
#undef STG_A
#undef STG_B
#undef RD_A
#undef RD_B
#undef DO_MFMA
#undef SYNC_LGKM
#undef ENDPH
}

__global__ __launch_bounds__(512, 2) void k_proj8(
    const ushort* __restrict__ A, const ushort* __restrict__ B,
    ushort* __restrict__ C, const float* __restrict__ bias) {
    gemm8p<0>(A, 512, 0L, B, 512, 0L, C, 1024, 0L,
              4, 512, bias, 0.f, nullptr, 0L);
}

__global__ __launch_bounds__(512, 2) void k_escore8(
    const ushort* __restrict__ A, const ushort* __restrict__ B,
    ushort* __restrict__ C, float* __restrict__ Z) {
    gemm8p<1>(A, 1024, 2048L * 1024, B, 1024, 2048L * 1024,
              C, 2048, 2048L * 2048, 8, 512,
              nullptr, 0.063758716f, Z, 2048L);
}

// ===== k_out: r8-proven 2-deep counted-vmcnt 128x128 core (unchanged) ======
__global__ __launch_bounds__(256) void k_out(
    const ushort* __restrict__ Ain, const ushort* __restrict__ Bin,
    float* __restrict__ Cout) {
    __shared__ ushort lA[2][8192];
    __shared__ ushort lB[2][8192];
    const int lda = 2048, ldb = 2048, ldc = 512, tiles_n = 4, K = 2048;
    const int b = blockIdx.y;
    const ushort* A = Ain + (size_t)b * 2048L * 2048;
    const ushort* B = Bin + (size_t)b * 512L * 2048;
    const int bx = xcd_swz(blockIdx.x, gridDim.x);
    const int tm = bx / tiles_n, tn = bx % tiles_n;
    const int t = threadIdx.x;
    const int l = t & 63, w = t >> 6;
    const int wr = w >> 1, wc = w & 1;

    size_t gA[4], gB[4];
    int dOf[4];
#pragma unroll
    for (int p = 0; p < 4; ++p) {
        int off = p * 4096 + t * 16;
        int row = off >> 7, kb = off & 127;
        int kswz = kb ^ ((row & 7) << 4);
        gA[p] = (size_t)(tm * 128 + row) * lda + (kswz >> 1);
        gB[p] = (size_t)(tn * 128 + row) * ldb + (kswz >> 1);
        dOf[p] = off;
    }
    auto stage = [&](int buf, int k0) {
#pragma unroll
        for (int p = 0; p < 4; ++p) {
            async_copy16(A + gA[p] + k0, (char*)lA[buf] + dOf[p]);
            async_copy16(B + gB[p] + k0, (char*)lB[buf] + dOf[p]);
        }
    };

    f32x4 acc[4][4];
#pragma unroll
    for (int i = 0; i < 4; ++i)
#pragma unroll
        for (int j = 0; j < 4; ++j) acc[i][j] = (f32x4){0.f, 0.f, 0.f, 0.f};

    const int nk = K >> 6;
    stage(0, 0);
    stage(1, 64);
    asm volatile("s_waitcnt vmcnt(8)" ::: "memory");
    __builtin_amdgcn_s_barrier();
    asm volatile("" ::: "memory");

    for (int kt = 0; kt < nk; ++kt) {
        const int cur = kt & 1;
        bf16x8 af[4][2], bg[4][2];
#pragma unroll
        for (int ks = 0; ks < 2; ++ks)
#pragma unroll
            for (int i = 0; i < 4; ++i) {
                int rowA = wr * 64 + i * 16 + (l & 15);
                int colA = (ks * 64 + (l >> 4) * 16) ^ ((rowA & 7) << 4);
                af[i][ks] = *(const bf16x8*)((const char*)lA[cur] + rowA * 128 + colA);
                int rowB = wc * 64 + i * 16 + (l & 15);
                int colB = (ks * 64 + (l >> 4) * 16) ^ ((rowB & 7) << 4);
                bg[i][ks] = *(const bf16x8*)((const char*)lB[cur] + rowB * 128 + colB);
            }
        asm volatile("s_waitcnt lgkmcnt(0)" ::: "memory");
        __builtin_amdgcn_sched_barrier(0);
        __builtin_amdgcn_s_barrier();
        asm volatile("" ::: "memory");
        if (kt + 2 < nk) stage(cur, (kt + 2) << 6);
        __builtin_amdgcn_sched_barrier(0);
        __builtin_amdgcn_s_setprio(1);
#pragma unroll
        for (int ks = 0; ks < 2; ++ks)
#pragma unroll
            for (int i = 0; i < 4; ++i)
#pragma unroll
                for (int j = 0; j < 4; ++j)
                    acc[i][j] = __builtin_amdgcn_mfma_f32_16x16x32_bf16(
                        af[i][ks], bg[j][ks], acc[i][j], 0, 0, 0);
        __builtin_amdgcn_s_setprio(0);
        if (kt + 2 < nk) {
            asm volatile("s_waitcnt vmcnt(8)" ::: "memory");
        } else {
            asm volatile("s_waitcnt vmcnt(0)" ::: "memory");
        }
        __builtin_amdgcn_s_barrier();
        asm volatile("" ::: "memory");
    }

    const int mb = tm * 128 + wr * 64;
    const int nb = tn * 128 + wc * 64;
    float* Cp = Cout + (size_t)b * 2048L * 512;
#pragma unroll
    for (int i = 0; i < 4; ++i)
#pragma unroll
        for (int j = 0; j < 4; ++j)
#pragma unroll
            for (int q = 0; q < 4; ++q) {
                int row = mb + i * 16 + (l >> 4) * 4 + q;
                int col = nb + j * 16 + (l & 15);
                Cp[(size_t)row * ldc + col] = acc[i][j][q];
            }
}

namespace {
struct AttrInit {
    AttrInit() {
        hipFuncSetAttribute(reinterpret_cast<const void*>(&k_proj8),
                            hipFuncAttributeMaxDynamicSharedMemorySize, 131072);
        hipFuncSetAttribute(reinterpret_cast<const void*>(&k_escore8),
                            hipFuncAttributeMaxDynamicSharedMemorySize, 131072);
    }
};
AttrInit attr_init_;
}

extern "C" void kernel_launch(void* const* d_in, const int* in_sizes, int n_in,
                              void* d_out, int out_size, void* d_ws, size_t ws_size,
                              hipStream_t stream) {
    const float* x  = (const float*)d_in[0];
    const float* Wq = (const float*)d_in[1];
    const float* bq = (const float*)d_in[2];
    const float* Wk = (const float*)d_in[3];
    const float* bk = (const float*)d_in[4];

    char* ws = (char*)d_ws;
    ushort* xb    = (ushort*)(ws);                 // 16 MB
    ushort* Wb    = (ushort*)(ws + 16777216);      //  1 MB
    float*  biasc = (float*) (ws + 17825792);      //  4 KB
    float*  Z     = (float*) (ws + 17829888);      // 64 KB (storage-indexed)
    ushort* qkb   = (ushort*)(ws + 17895424);      // 32 MB (reused as xzT)
    ushort* E     = (ushort*)(ws + 51449856);      // 64 MB
    ushort* xzT   = qkb;

    (void)hipMemsetAsync(Z, 0, 16384 * 4, stream);

    k_cvt<<<8192, 256, 0, stream>>>(
        (const float4*)x, (const float4*)Wq, (const float4*)Wk,
        (const float4*)bq, (const float4*)bk,
        (bf16x4*)xb, (bf16x4*)Wb, (float4*)biasc);

    // proj: qk[m, P(h)] = x . W^T + bias  (M=16384, N=1024, K=512)
    k_proj8<<<dim3(256, 1), 512, 131072, stream>>>(xb, Wb, qkb, biasc);

    // E-pass: E[b][m][P(n)] = exp2(scale2 * k[m].q[n]); Z_s += col sums
    k_escore8<<<dim3(64, 8), 512, 131072, stream>>>(qkb + 512, qkb, E, Z);

    // fold: xzT[b][d][s] = bf16(x[b][Q(s)][d] / Z_s[s])
    k_fold<<<dim3(256, 8), 256, 0, stream>>>((const __bf16*)xb, Z, xzT);

    // out: out[b][m][d] = sum_s E[b][m][s] * xzT[b][d][s]   (fp32)
    k_out<<<dim3(64, 8), 256, 0, stream>>>(E, xzT, (float*)d_out);
}